// Round 17
// baseline (310.106 us; speedup 1.0000x reference)
//
#include <hip/hip_runtime.h>
#include <hip/hip_bf16.h>
#include <math.h>

typedef unsigned short u16;
typedef unsigned int u32;
typedef __attribute__((ext_vector_type(8))) short bf16x8;
typedef __attribute__((ext_vector_type(4))) float f32x4;

// B=4, T=2048, D=1024, H=16, DK=64, DV=128, CHUNK=64, N_CHUNKS=32

__device__ __forceinline__ u16 f2bf(float f) {
  union { float f; unsigned u; } a; a.f = f;
  unsigned u = a.u;
  unsigned r = (u + 0x7fffu + ((u >> 16) & 1u)) >> 16;
  return (u16)r;
}
__device__ __forceinline__ float bf2f(u16 s) {
  union { unsigned u; float f; } a; a.u = ((unsigned)s) << 16; return a.f;
}

__global__ void k_sentinel(float* out) {
  if (threadIdx.x == 0 && blockIdx.x == 0) out[0] = 1.0e6f;
}

// exact split: f32 -> bf16 hi + bf16 lo (hi+lo == f to ~2^-16 rel)
__device__ __forceinline__ void split8r(const float* t, bf16x8& hi, bf16x8& lo) {
#pragma unroll
  for (int m = 0; m < 8; ++m) {
    union { float f; u32 u; } c; c.f = t[m];
    union { u32 u; float f; } hf; hf.u = c.u & 0xffff0000u;
    union { float f; u32 u; } lw; lw.f = t[m] - hf.f;
    hi[m] = (short)(u16)(c.u >> 16);
    lo[m] = (short)(u16)(lw.u >> 16);
  }
}
__device__ __forceinline__ void split8p(const float* __restrict__ p, bf16x8& hi, bf16x8& lo) {
  f32x4 a = *(const f32x4*)p;
  f32x4 b = *(const f32x4*)(p + 4);
  float t[8];
  t[0]=a[0]; t[1]=a[1]; t[2]=a[2]; t[3]=a[3]; t[4]=b[0]; t[5]=b[1]; t[6]=b[2]; t[7]=b[3];
  split8r(t, hi, lo);
}

// raw barrier that does NOT drain vmcnt; lgkmcnt(0) first so producer LDS
// writes are visible across the barrier.
__device__ __forceinline__ void bar_lds() {
  asm volatile("s_waitcnt lgkmcnt(0)" ::: "memory");
  __builtin_amdgcn_sched_barrier(0);
  __builtin_amdgcn_s_barrier();
}

// barrier that drains vmcnt (gload_lds staging pipelines)
__device__ __forceinline__ void bar_vm() {
  asm volatile("s_waitcnt vmcnt(0)" ::: "memory");
  __builtin_amdgcn_sched_barrier(0);
  __builtin_amdgcn_s_barrier();
}

// async global->LDS, 16B per lane; lds base wave-uniform (HW adds lane*16)
__device__ __forceinline__ void gload16(const u16* g, u16* l) {
  __builtin_amdgcn_global_load_lds(
      (const __attribute__((address_space(1))) unsigned int*)g,
      (__attribute__((address_space(3))) unsigned int*)l, 16, 0, 0);
}

// ---------- x f32 -> bf16 ----------
__global__ __launch_bounds__(256) void k_cvt_x(const float* __restrict__ src, u16* __restrict__ dst) {
  int i = blockIdx.x * 256 + threadIdx.x;
  float4 v = ((const float4*)src)[i];
  ushort4 o;
  o.x = f2bf(v.x); o.y = f2bf(v.y); o.z = f2bf(v.z); o.w = f2bf(v.w);
  ((ushort4*)dst)[i] = o;
}

// ---------- RoPE cos/sin table (bit-identical expressions to proven k_rope) ----------
__global__ __launch_bounds__(256) void k_ropetab(float2* __restrict__ tab) {
  int idx = blockIdx.x * 256 + threadIdx.x;   // 2048*32
  int t = idx >> 5, i = idx & 31;
  float invf = powf(10000.f, -(float)i * (1.f / 32.f));
  float ang = (float)t * invf;
  float2 cs; cs.x = cosf(ang); cs.y = sinf(ang);
  tab[idx] = cs;
}

// ---------- all weight transposes in one launch (z-ranged) ----------
__global__ __launch_bounds__(256) void k_transpose_all(
    const float* __restrict__ Wq, const float* __restrict__ Wk, const float* __restrict__ Wv,
    const float* __restrict__ Wg, const float* __restrict__ Wo,
    u16* __restrict__ Wqkb, u16* __restrict__ Wvgb, u16* __restrict__ Wob) {
  int z = blockIdx.x;
  const float* src; u16* dst; int K, N, bx, by;
  if (z < 1024)      { src = Wq; dst = Wqkb;                       K = 1024; N = 1024; int r = z;        bx = r & 31; by = r >> 5; }
  else if (z < 2048) { src = Wk; dst = Wqkb + (size_t)1024 * 1024; K = 1024; N = 1024; int r = z - 1024; bx = r & 31; by = r >> 5; }
  else if (z < 4096) { src = Wv; dst = Wvgb;                       K = 1024; N = 2048; int r = z - 2048; bx = r & 63; by = r >> 6; }
  else if (z < 6144) { src = Wg; dst = Wvgb + (size_t)2048 * 1024; K = 1024; N = 2048; int r = z - 4096; bx = r & 63; by = r >> 6; }
  else               { src = Wo; dst = Wob;                        K = 2048; N = 1024; int r = z - 6144; bx = r & 31; by = r >> 5; }
  __shared__ float tile[32][33];
  int n0 = bx * 32, k0 = by * 32;
  int tx = threadIdx.x & 31, ty = threadIdx.x >> 5;
  for (int r = 0; r < 32; r += 8)
    tile[ty + r][tx] = src[(size_t)(k0 + ty + r) * N + n0 + tx];
  __syncthreads();
  for (int r = 0; r < 32; r += 8)
    dst[(size_t)(n0 + ty + r) * K + k0 + tx] = f2bf(tile[tx][ty + r]);
}

// BK=32 staging for 256x128 block tile: A = 16 x 1KB segs, B = 8 x 1KB segs.
// st_16x32 swizzle: dest linear (gload_lds), source pre-swizzled; read same XOR.
#define STG(t, sl)                                                                  \
  {                                                                                 \
    _Pragma("unroll")                                                               \
    for (int q = 0; q < 4; ++q) {                                                   \
      int s = w * 4 + q;                                                            \
      int dByte = s * 1024 + lane * 16;                                             \
      int u = dByte ^ (((dByte >> 9) & 1) << 5);                                    \
      int row = u >> 6, cb = u & 63;                                                \
      gload16(&A[(size_t)(i0 + row) * K + (t) * 32 + (cb >> 1)], &As[sl][s * 512]); \
    }                                                                               \
    _Pragma("unroll")                                                               \
    for (int q = 0; q < 2; ++q) {                                                   \
      int s = w * 2 + q;                                                            \
      int dByte = s * 1024 + lane * 16;                                             \
      int u = dByte ^ (((dByte >> 9) & 1) << 5);                                    \
      int row = u >> 6, cb = u & 63;                                                \
      gload16(&Bt[(size_t)(n0 + row) * K + (t) * 32 + (cb >> 1)], &Bs[sl][s * 512]);\
    }                                                                               \
  }

// ---------- merged projection GEMM: 256x128 tile, wave 128x64 (8x4), BK=32 dbuf ----------
// C[8192][6144] = xb * Wqkvg^T ; cols<2048 -> qk f32 + table-RoPE; else vg bf16.
// Reads/MFMA 0.375 (was 0.5) -> raises the LDS-BW ceiling. K order ascending 32 -> bit-identical.
__global__ __launch_bounds__(256, 2) void k_gemm_qkvg(const u16* __restrict__ A, const u16* __restrict__ Bt,
                                                      float* __restrict__ qk, u16* __restrict__ vg,
                                                      const float2* __restrict__ tab, int K) {
  __shared__ __attribute__((aligned(16))) u16 As[2][256 * 32];
  __shared__ __attribute__((aligned(16))) u16 Bs[2][128 * 32];
  int nbx = gridDim.x;
  int id = blockIdx.y * nbx + blockIdx.x;
  int cpx = (nbx * gridDim.y) >> 3;
  int sw = (id & 7) * cpx + (id >> 3);
  int bx = sw % nbx, by = sw / nbx;
  int i0 = by * 256, n0 = bx * 128;
  int tid = threadIdx.x;
  int lane = tid & 63, w = tid >> 6;
  int wr = (w >> 1) * 128, wc = (w & 1) * 64;
  f32x4 acc[8][4];
#pragma unroll
  for (int m = 0; m < 8; ++m)
#pragma unroll
    for (int n = 0; n < 4; ++n) acc[m][n] = (f32x4){0.f, 0.f, 0.f, 0.f};
  int fr = lane & 15, kq = lane >> 4;
  int nkt = K >> 5;

  STG(0, 0);
  bar_vm();
  for (int t = 0; t < nkt; ++t) {
    int sl = t & 1;
    if (t + 1 < nkt) STG(t + 1, sl ^ 1);    // prefetch overlaps this tile's MFMA
    bf16x8 af[8], bfr[4];
#pragma unroll
    for (int m = 0; m < 8; ++m) {
      int rr = wr + m * 16 + fr;
      int idx = (rr * 32 + kq * 8) ^ (((rr >> 3) & 1) << 4);
      af[m] = *(const bf16x8*)&As[sl][idx];
    }
#pragma unroll
    for (int n = 0; n < 4; ++n) {
      int rr = wc + n * 16 + fr;
      int idx = (rr * 32 + kq * 8) ^ (((rr >> 3) & 1) << 4);
      bfr[n] = *(const bf16x8*)&Bs[sl][idx];
    }
    __builtin_amdgcn_s_setprio(1);
#pragma unroll
    for (int m = 0; m < 8; ++m)
#pragma unroll
      for (int n = 0; n < 4; ++n)
        acc[m][n] = __builtin_amdgcn_mfma_f32_16x16x32_bf16(af[m], bfr[n], acc[m][n], 0, 0, 0);
    __builtin_amdgcn_s_setprio(0);
    bar_vm();                               // next tile landed; slot reads done
  }

  int rb = (lane >> 4) * 4, cb2 = lane & 15;
  if (n0 < 2048) {
    float scale = (n0 < 1024) ? 0.125f : 1.0f;
#pragma unroll
    for (int m = 0; m < 8; ++m)
#pragma unroll
      for (int n = 0; n < 2; ++n) {
        int gc = n0 + wc + n * 16 + cb2;
        int ii = n * 16 + cb2;
#pragma unroll
        for (int r = 0; r < 4; ++r) {
          int gr = i0 + wr + m * 16 + rb + r;
          int t = gr & 2047;
          float2 cs = tab[t * 32 + ii];
          float q1 = acc[m][n][r], q2 = acc[m][n + 2][r];
          qk[(size_t)gr * 2048 + gc]      = (q1 * cs.x - q2 * cs.y) * scale;
          qk[(size_t)gr * 2048 + gc + 32] = (q2 * cs.x + q1 * cs.y) * scale;
        }
      }
  } else {
#pragma unroll
    for (int m = 0; m < 8; ++m)
#pragma unroll
      for (int n = 0; n < 4; ++n) {
        int gr = i0 + wr + m * 16 + rb;
        int gc = n0 - 2048 + wc + n * 16 + cb2;
#pragma unroll
        for (int r = 0; r < 4; ++r)
          vg[(size_t)(gr + r) * 4096 + gc] = f2bf(acc[m][n][r]);
      }
  }
}

// ---------- output GEMM: same 256x128 / 128x64-wave structure ----------
__global__ __launch_bounds__(256, 2) void k_gemm_out(const u16* __restrict__ A, const u16* __restrict__ Bt,
                                                     float* __restrict__ Cv, int N, int K) {
  __shared__ __attribute__((aligned(16))) u16 As[2][256 * 32];
  __shared__ __attribute__((aligned(16))) u16 Bs[2][128 * 32];
  int nbx = gridDim.x;
  int id = blockIdx.y * nbx + blockIdx.x;
  int cpx = (nbx * gridDim.y) >> 3;
  int sw = (id & 7) * cpx + (id >> 3);
  int bx = sw % nbx, by = sw / nbx;
  int i0 = by * 256, n0 = bx * 128;
  int tid = threadIdx.x;
  int lane = tid & 63, w = tid >> 6;
  int wr = (w >> 1) * 128, wc = (w & 1) * 64;
  f32x4 acc[8][4];
#pragma unroll
  for (int m = 0; m < 8; ++m)
#pragma unroll
    for (int n = 0; n < 4; ++n) acc[m][n] = (f32x4){0.f, 0.f, 0.f, 0.f};
  int fr = lane & 15, kq = lane >> 4;
  int nkt = K >> 5;

  STG(0, 0);
  bar_vm();
  for (int t = 0; t < nkt; ++t) {
    int sl = t & 1;
    if (t + 1 < nkt) STG(t + 1, sl ^ 1);
    bf16x8 af[8], bfr[4];
#pragma unroll
    for (int m = 0; m < 8; ++m) {
      int rr = wr + m * 16 + fr;
      int idx = (rr * 32 + kq * 8) ^ (((rr >> 3) & 1) << 4);
      af[m] = *(const bf16x8*)&As[sl][idx];
    }
#pragma unroll
    for (int n = 0; n < 4; ++n) {
      int rr = wc + n * 16 + fr;
      int idx = (rr * 32 + kq * 8) ^ (((rr >> 3) & 1) << 4);
      bfr[n] = *(const bf16x8*)&Bs[sl][idx];
    }
    __builtin_amdgcn_s_setprio(1);
#pragma unroll
    for (int m = 0; m < 8; ++m)
#pragma unroll
      for (int n = 0; n < 4; ++n)
        acc[m][n] = __builtin_amdgcn_mfma_f32_16x16x32_bf16(af[m], bfr[n], acc[m][n], 0, 0, 0);
    __builtin_amdgcn_s_setprio(0);
    bar_vm();
  }

  int rb = (lane >> 4) * 4, cb2 = lane & 15;
#pragma unroll
  for (int m = 0; m < 8; ++m)
#pragma unroll
    for (int n = 0; n < 4; ++n) {
      int gr = i0 + wr + m * 16 + rb;
      int gc = n0 + wc + n * 16 + cb2;
#pragma unroll
      for (int r = 0; r < 4; ++r)
        Cv[(size_t)(gr + r) * N + gc] = acc[m][n][r];
    }
}

// ---------- Fused retention v7 (proven, frozen) ----------
__global__ __launch_bounds__(512) void k_retention(const float* __restrict__ qk, const u16* __restrict__ vg,
                                                   const float* __restrict__ gnw, u16* __restrict__ og) {
  int bh = blockIdx.x & 63, rq = blockIdx.x >> 6;
  int h = bh & 15, b = bh >> 4;
  int gi0 = rq * 16;

  __shared__ __attribute__((aligned(16))) float qs[16][68];
  __shared__ __attribute__((aligned(16))) float ks[64][68];
  __shared__ __attribute__((aligned(16))) u16 vst[128][88];
  __shared__ __attribute__((aligned(16))) u16 kta_h[8][520];
  __shared__ __attribute__((aligned(16))) u16 kta_l[8][520];
  __shared__ __attribute__((aligned(16))) u16 pa_h[16][68];
  __shared__ __attribute__((aligned(16))) u16 pa_l[16][68];
  __shared__ __attribute__((aligned(16))) u16 sst_h[8][1040];
  __shared__ __attribute__((aligned(16))) u16 sst_l[8][1040];
  __shared__ float dpow[72];
  __shared__ float ssred[8][16];

  int tid = threadIdx.x;
  int w = tid >> 6, l = tid & 63;
  int fr = l & 15, fq = l >> 4;
  float gamma = 1.f - exp2f(-5.f - (float)h);
  if (tid <= 64) dpow[tid] = powf(gamma, (float)tid);
  for (int c = tid; c < 4160; c += 512) { ((u32*)sst_h)[c] = 0; ((u32*)sst_l)[c] = 0; }
  __syncthreads();
  float cdec = dpow[64];

  int e0 = w * 16;
  float gww = gnw[e0 + fr];
  int khmax = (rq < 2) ? 1 : 2;

  int qi = tid >> 4, qd4 = (tid & 15) * 4;
  int sj = tid >> 3, sdg = (tid & 7) * 8;
  int vjp = tid & 31, ve8 = (tid >> 5) * 8;

  f32x4 Sacc[4][2];
#pragma unroll
  for (int dt = 0; dt < 4; ++dt)
#pragma unroll
    for (int nt = 0; nt < 2; ++nt) Sacc[dt][nt] = (f32x4){0.f, 0.f, 0.f, 0.f};

  f32x4 pq = (f32x4){0.f, 0.f, 0.f, 0.f};
  f32x4 pk0, pk1;
  bf16x8 pva, pvb;
  {
    int rowbase = b * 2048;
    if (tid < 256) pq = *(const f32x4*)&qk[(size_t)(rowbase + gi0 + qi) * 2048 + h * 64 + qd4];
    const float* kr = &qk[(size_t)(rowbase + sj) * 2048 + 1024 + h * 64 + sdg];
    pk0 = *(const f32x4*)kr;
    pk1 = *(const f32x4*)(kr + 4);
    const u16* vr = &vg[(size_t)(rowbase + 2 * vjp) * 4096 + h * 128 + ve8];
    pva = *(const bf16x8*)vr;
    pvb = *(const bf16x8*)(vr + 4096);
  }

  for (int n = 0; n < 32; ++n) {
    int rowbase = b * 2048 + n * 64;
    if (tid < 256) *(f32x4*)&qs[qi][qd4] = pq;
    {
      *(f32x4*)&ks[sj][sdg] = pk0;
      *(f32x4*)&ks[sj][sdg + 4] = pk1;
      float kdv = dpow[63 - sj];
      float kd[8];
#pragma unroll
      for (int m = 0; m < 4; ++m) { kd[m] = pk0[m] * kdv; kd[m + 4] = pk1[m] * kdv; }
      bf16x8 kh8, kl8;
      split8r(kd, kh8, kl8);
      int J = sj >> 3, s = sj & 7, dh = tid & 7;
#pragma unroll
      for (int m = 0; m < 8; ++m) {
        int blk = (dh * 8) | (m ^ dh);
        kta_h[J][blk * 8 + s] = (u16)kh8[m];
        kta_l[J][blk * 8 + s] = (u16)kl8[m];
      }
#pragma unroll
      for (int m = 0; m < 8; ++m)
        *(u32*)&vst[ve8 + m][2 * vjp] = (u32)(u16)pva[m] | ((u32)(u16)pvb[m] << 16);
    }
    __syncthreads();
    if (n < 31) {
      int rb2 = rowbase + 64;
      if (tid < 256) pq = *(const f32x4*)&qk[(size_t)(rb2 + gi0 + qi) * 2048 + h * 64 + qd4];
      const float* kr = &qk[(size_t)(rb2 + sj) * 2048 + 1024 + h * 64 + sdg];
      pk0 = *(const f32x4*)kr;
      pk1 = *(const f32x4*)(kr + 4);
      const u16* vr = &vg[(size_t)(rb2 + 2 * vjp) * 4096 + h * 128 + ve8];
      pva = *(const bf16x8*)vr;
      pvb = *(const bf16x8*)(vr + 4096);
    }
    bf16x8 qhc[2], qlc[2];
    split8p(&qs[fr][fq * 8], qhc[0], qlc[0]);
    split8p(&qs[fr][32 + fq * 8], qhc[1], qlc[1]);
    if (w < 4) {
      int ct = w;
      f32x4 at = (f32x4){0.f, 0.f, 0.f, 0.f};
      if (16 * ct <= gi0 + 15) {
#pragma unroll
        for (int kh = 0; kh < 2; ++kh) {
          bf16x8 kbh, kbl;
          split8p(&ks[16 * ct + fr][kh * 32 + fq * 8], kbh, kbl);
          at = __builtin_amdgcn_mfma_f32_16x16x32_bf16(kbh, qhc[kh], at, 0, 0, 0);
          at = __builtin_amdgcn_mfma_f32_16x16x32_bf16(kbl, qhc[kh], at, 0, 0, 0);
          at = __builtin_amdgcn_mfma_f32_16x16x32_bf16(kbh, qlc[kh], at, 0, 0, 0);
        }
      }
      int jb = 16 * ct + fq * 4;
      ushort4 wh, wl;
#pragma unroll
      for (int r = 0; r < 4; ++r) {
        int s = gi0 + fr - (jb + r);
        float val = (s >= 0) ? at[r] * dpow[s] : 0.f;
        union { float f; u32 u; } c; c.f = val;
        union { u32 u; float f; } hf; hf.u = c.u & 0xffff0000u;
        union { float f; u32 u; } lw; lw.f = val - hf.f;
        ((u16*)&wh)[r] = (u16)(c.u >> 16);
        ((u16*)&wl)[r] = (u16)(lw.u >> 16);
      }
      *(ushort4*)&pa_h[fr][jb] = wh;
      *(ushort4*)&pa_l[fr][jb] = wl;
    } else if (n < 31) {
      int eb = (w - 4) * 32;
#pragma unroll
      for (int dt = 0; dt < 4; ++dt)
#pragma unroll
        for (int nt = 0; nt < 2; ++nt)
#pragma unroll
          for (int r = 0; r < 4; ++r) Sacc[dt][nt][r] *= cdec;
      bf16x8 bv[2][2];
#pragma unroll
      for (int kh2 = 0; kh2 < 2; ++kh2)
#pragma unroll
        for (int nt = 0; nt < 2; ++nt)
          bv[kh2][nt] = *(const bf16x8*)&vst[eb + nt * 16 + fr][kh2 * 32 + fq * 8];
#pragma unroll
      for (int kh2 = 0; kh2 < 2; ++kh2) {
#pragma unroll
        for (int dt = 0; dt < 4; ++dt) {
          int d = dt * 16 + fr;
          int blk = d ^ ((dt * 2 + (fr >> 3)) & 7);
          bf16x8 ah = *(const bf16x8*)&kta_h[kh2 * 4 + fq][blk * 8];
          bf16x8 al = *(const bf16x8*)&kta_l[kh2 * 4 + fq][blk * 8];
#pragma unroll
          for (int nt = 0; nt < 2; ++nt) {
            Sacc[dt][nt] = __builtin_amdgcn_mfma_f32_16x16x32_bf16(ah, bv[kh2][nt], Sacc[dt][nt], 0, 0, 0);
            Sacc[dt][nt] = __builtin_amdgcn_mfma_f32_16x16x32_bf16(al, bv[kh2][nt], Sacc[dt][nt], 0, 0, 0);
          }
        }
      }
    }
    bar_lds();
    f32x4 o1 = (f32x4){0.f, 0.f, 0.f, 0.f};
    f32x4 o2 = (f32x4){0.f, 0.f, 0.f, 0.f};
#pragma unroll
    for (int kh2 = 0; kh2 < 2; ++kh2) {
      bf16x8 sh = *(const bf16x8*)&sst_h[kh2 * 4 + fq][(e0 + fr) * 8];
      bf16x8 sl = *(const bf16x8*)&sst_l[kh2 * 4 + fq][(e0 + fr) * 8];
      o2 = __builtin_amdgcn_mfma_f32_16x16x32_bf16(qhc[kh2], sh, o2, 0, 0, 0);
      o2 = __builtin_amdgcn_mfma_f32_16x16x32_bf16(qhc[kh2], sl, o2, 0, 0, 0);
      o2 = __builtin_amdgcn_mfma_f32_16x16x32_bf16(qlc[kh2], sh, o2, 0, 0, 0);
      if (kh2 < khmax) {
        bf16x8 ph = *(const bf16x8*)&pa_h[fr][kh2 * 32 + fq * 8];
        bf16x8 pl = *(const bf16x8*)&pa_l[fr][kh2 * 32 + fq * 8];
        bf16x8 bvv = *(const bf16x8*)&vst[e0 + fr][kh2 * 32 + fq * 8];
        o1 = __builtin_amdgcn_mfma_f32_16x16x32_bf16(ph, bvv, o1, 0, 0, 0);
        o1 = __builtin_amdgcn_mfma_f32_16x16x32_bf16(pl, bvv, o1, 0, 0, 0);
      }
    }
    float ofin[4], ssp[4];
#pragma unroll
    for (int r = 0; r < 4; ++r) {
      int gi = gi0 + fq * 4 + r;
      ofin[r] = o1[r] + dpow[gi + 1] * o2[r];
      ssp[r] = ofin[r] * ofin[r];
    }
#pragma unroll
    for (int r = 0; r < 4; ++r) {
      ssp[r] += __shfl_xor(ssp[r], 1, 64);
      ssp[r] += __shfl_xor(ssp[r], 2, 64);
      ssp[r] += __shfl_xor(ssp[r], 4, 64);
      ssp[r] += __shfl_xor(ssp[r], 8, 64);
    }
    if (fr == 0) {
#pragma unroll
      for (int r = 0; r < 4; ++r) ssred[w][fq * 4 + r] = ssp[r];
    }
    bar_lds();
#pragma unroll
    for (int r = 0; r < 4; ++r) {
      int i16 = fq * 4 + r;
      float tot = 0.f;
#pragma unroll
      for (int w2 = 0; w2 < 8; ++w2) tot += ssred[w2][i16];
      float rms = rsqrtf(tot * (1.f / 128.f) + 1e-5f);
      int grow = rowbase + gi0 + i16;
      float g = bf2f(vg[(size_t)grow * 4096 + 2048 + h * 128 + e0 + fr]);
      float y = ofin[r] * rms * gww * (g / (1.f + expf(-g)));
      og[(size_t)grow * 2048 + h * 128 + e0 + fr] = f2bf(y);
    }
    if (w >= 4 && n < 31) {
      int eb = (w - 4) * 32;
#pragma unroll
      for (int dt = 0; dt < 4; ++dt) {
        int g = dt * 2 + (fq >> 1);
#pragma unroll
        for (int nt = 0; nt < 2; ++nt) {
          int e = eb + nt * 16 + fr;
          ushort4 wh, wl;
#pragma unroll
          for (int r = 0; r < 4; ++r) {
            union { float f; u32 u; } c; c.f = Sacc[dt][nt][r];
            union { u32 u; float f; } hf; hf.u = c.u & 0xffff0000u;
            union { float f; u32 u; } lw; lw.f = Sacc[dt][nt][r] - hf.f;
            ((u16*)&wh)[r] = (u16)(c.u >> 16);
            ((u16*)&wl)[r] = (u16)(lw.u >> 16);
          }
          int idx = e * 8 + (fq & 1) * 4;
          *(ushort4*)&sst_h[g][idx] = wh;
          *(ushort4*)&sst_l[g][idx] = wl;
        }
      }
    }
  }
}

extern "C" void kernel_launch(void* const* d_in, const int* in_sizes, int n_in,
                              void* d_out, int out_size, void* d_ws, size_t ws_size,
                              hipStream_t stream) {
  const float* x   = (const float*)d_in[0];
  const float* Wq  = (const float*)d_in[1];
  const float* Wk  = (const float*)d_in[2];
  const float* Wv  = (const float*)d_in[3];
  const float* Wg  = (const float*)d_in[4];
  const float* Wo  = (const float*)d_in[5];
  const float* gnw = (const float*)d_in[6];
  float* out = (float*)d_out;

  const size_t MB = 1024 * 1024;
  char* ws = (char*)d_ws;
  u16*   xb   = (u16*)(ws + 0 * MB);
  u16*   Wqkb = (u16*)(ws + 16 * MB);     // [2048][1024]
  u16*   Wvgb = (u16*)(ws + 20 * MB);     // [4096][1024]
  float2* tab = (float2*)(ws + 28 * MB);  // 512 KB rope table
  float* qk   = (float*)(ws + 32 * MB);
  u16*   vg   = (u16*)(ws + 96 * MB);
  u16*   Wob  = (u16*)(ws + 160 * MB);
  u16*   og   = (u16*)(ws + 0 * MB);      // overlay (xb/W dead by then)
  const size_t NEED = 164 * MB;
  if (ws_size < NEED) {
    k_sentinel<<<1, 64, 0, stream>>>(out);
    return;
  }

  k_cvt_x<<<8192, 256, 0, stream>>>(x, xb);
  k_ropetab<<<256, 256, 0, stream>>>(tab);
  k_transpose_all<<<8192, 256, 0, stream>>>(Wq, Wk, Wv, Wg, Wo, Wqkb, Wvgb, Wob);

  k_gemm_qkvg<<<dim3(48, 32), 256, 0, stream>>>(xb, Wqkb, qk, vg, tab, 1024);
  k_retention<<<256, 512, 0, stream>>>(qk, vg, gnw, og);
  k_gemm_out<<<dim3(8, 32), 256, 0, stream>>>(og, Wob, out, 1024, 2048);
}

// Round 18
// 281.659 us; speedup vs baseline: 1.1010x; 1.1010x over previous
//
#include <hip/hip_runtime.h>
#include <hip/hip_bf16.h>
#include <math.h>

typedef unsigned short u16;
typedef unsigned int u32;
typedef __attribute__((ext_vector_type(8))) short bf16x8;
typedef __attribute__((ext_vector_type(4))) float f32x4;

// B=4, T=2048, D=1024, H=16, DK=64, DV=128, CHUNK=64, N_CHUNKS=32

__device__ __forceinline__ u16 f2bf(float f) {
  union { float f; unsigned u; } a; a.f = f;
  unsigned u = a.u;
  unsigned r = (u + 0x7fffu + ((u >> 16) & 1u)) >> 16;
  return (u16)r;
}
__device__ __forceinline__ float bf2f(u16 s) {
  union { unsigned u; float f; } a; a.u = ((unsigned)s) << 16; return a.f;
}

__global__ void k_sentinel(float* out) {
  if (threadIdx.x == 0 && blockIdx.x == 0) out[0] = 1.0e6f;
}

// exact split: f32 -> bf16 hi + bf16 lo (hi+lo == f to ~2^-16 rel)
__device__ __forceinline__ void split8r(const float* t, bf16x8& hi, bf16x8& lo) {
#pragma unroll
  for (int m = 0; m < 8; ++m) {
    union { float f; u32 u; } c; c.f = t[m];
    union { u32 u; float f; } hf; hf.u = c.u & 0xffff0000u;
    union { float f; u32 u; } lw; lw.f = t[m] - hf.f;
    hi[m] = (short)(u16)(c.u >> 16);
    lo[m] = (short)(u16)(lw.u >> 16);
  }
}
__device__ __forceinline__ void split8p(const float* __restrict__ p, bf16x8& hi, bf16x8& lo) {
  f32x4 a = *(const f32x4*)p;
  f32x4 b = *(const f32x4*)(p + 4);
  float t[8];
  t[0]=a[0]; t[1]=a[1]; t[2]=a[2]; t[3]=a[3]; t[4]=b[0]; t[5]=b[1]; t[6]=b[2]; t[7]=b[3];
  split8r(t, hi, lo);
}

// raw barrier that does NOT drain vmcnt; lgkmcnt(0) first so producer LDS
// writes are visible across the barrier.
__device__ __forceinline__ void bar_lds() {
  asm volatile("s_waitcnt lgkmcnt(0)" ::: "memory");
  __builtin_amdgcn_sched_barrier(0);
  __builtin_amdgcn_s_barrier();
}

// barrier that drains vmcnt (gload_lds staging pipelines)
__device__ __forceinline__ void bar_vm() {
  asm volatile("s_waitcnt vmcnt(0)" ::: "memory");
  __builtin_amdgcn_sched_barrier(0);
  __builtin_amdgcn_s_barrier();
}

// async global->LDS, 16B per lane; lds base wave-uniform (HW adds lane*16)
__device__ __forceinline__ void gload16(const u16* g, u16* l) {
  __builtin_amdgcn_global_load_lds(
      (const __attribute__((address_space(1))) unsigned int*)g,
      (__attribute__((address_space(3))) unsigned int*)l, 16, 0, 0);
}

// ---------- x f32 -> bf16 ----------
__global__ __launch_bounds__(256) void k_cvt_x(const float* __restrict__ src, u16* __restrict__ dst) {
  int i = blockIdx.x * 256 + threadIdx.x;
  float4 v = ((const float4*)src)[i];
  ushort4 o;
  o.x = f2bf(v.x); o.y = f2bf(v.y); o.z = f2bf(v.z); o.w = f2bf(v.w);
  ((ushort4*)dst)[i] = o;
}

// ---------- RoPE cos/sin table (bit-identical expressions to proven k_rope) ----------
__global__ __launch_bounds__(256) void k_ropetab(float2* __restrict__ tab) {
  int idx = blockIdx.x * 256 + threadIdx.x;   // 2048*32
  int t = idx >> 5, i = idx & 31;
  float invf = powf(10000.f, -(float)i * (1.f / 32.f));
  float ang = (float)t * invf;
  float2 cs; cs.x = cosf(ang); cs.y = sinf(ang);
  tab[idx] = cs;
}

// ---------- all weight transposes in one launch (z-ranged) ----------
__global__ __launch_bounds__(256) void k_transpose_all(
    const float* __restrict__ Wq, const float* __restrict__ Wk, const float* __restrict__ Wv,
    const float* __restrict__ Wg, const float* __restrict__ Wo,
    u16* __restrict__ Wqkb, u16* __restrict__ Wvgb, u16* __restrict__ Wob) {
  int z = blockIdx.x;
  const float* src; u16* dst; int K, N, bx, by;
  if (z < 1024)      { src = Wq; dst = Wqkb;                       K = 1024; N = 1024; int r = z;        bx = r & 31; by = r >> 5; }
  else if (z < 2048) { src = Wk; dst = Wqkb + (size_t)1024 * 1024; K = 1024; N = 1024; int r = z - 1024; bx = r & 31; by = r >> 5; }
  else if (z < 4096) { src = Wv; dst = Wvgb;                       K = 1024; N = 2048; int r = z - 2048; bx = r & 63; by = r >> 6; }
  else if (z < 6144) { src = Wg; dst = Wvgb + (size_t)2048 * 1024; K = 1024; N = 2048; int r = z - 4096; bx = r & 63; by = r >> 6; }
  else               { src = Wo; dst = Wob;                        K = 2048; N = 1024; int r = z - 6144; bx = r & 31; by = r >> 5; }
  __shared__ float tile[32][33];
  int n0 = bx * 32, k0 = by * 32;
  int tx = threadIdx.x & 31, ty = threadIdx.x >> 5;
  for (int r = 0; r < 32; r += 8)
    tile[ty + r][tx] = src[(size_t)(k0 + ty + r) * N + n0 + tx];
  __syncthreads();
  for (int r = 0; r < 32; r += 8)
    dst[(size_t)(n0 + ty + r) * K + k0 + tx] = f2bf(tile[tx][ty + r]);
}

// BK=32 staging for 256x128 block tile (qkvg): A = 16 x 1KB segs, B = 8 x 1KB segs.
#define STG_P(t, sl)                                                                \
  {                                                                                 \
    _Pragma("unroll")                                                               \
    for (int q = 0; q < 4; ++q) {                                                   \
      int s = w * 4 + q;                                                            \
      int dByte = s * 1024 + lane * 16;                                             \
      int u = dByte ^ (((dByte >> 9) & 1) << 5);                                    \
      int row = u >> 6, cb = u & 63;                                                \
      gload16(&A[(size_t)(i0 + row) * K + (t) * 32 + (cb >> 1)], &As[sl][s * 512]); \
    }                                                                               \
    _Pragma("unroll")                                                               \
    for (int q = 0; q < 2; ++q) {                                                   \
      int s = w * 2 + q;                                                            \
      int dByte = s * 1024 + lane * 16;                                             \
      int u = dByte ^ (((dByte >> 9) & 1) << 5);                                    \
      int row = u >> 6, cb = u & 63;                                                \
      gload16(&Bt[(size_t)(n0 + row) * K + (t) * 32 + (cb >> 1)], &Bs[sl][s * 512]);\
    }                                                                               \
  }

// BK=64 staging for 128x128 tile (out-GEMM): two [128][32] subtiles per K-step.
#define STG64_O(t, sl)                                                                 \
  {                                                                                    \
    _Pragma("unroll")                                                                  \
    for (int kk = 0; kk < 2; ++kk) {                                                   \
      _Pragma("unroll")                                                                \
      for (int q = 0; q < 2; ++q) {                                                    \
        int s = w * 2 + q;                                                             \
        int dByte = s * 1024 + lane * 16;                                              \
        int u = dByte ^ (((dByte >> 9) & 1) << 5);                                     \
        int row = u >> 6, cb = u & 63;                                                 \
        gload16(&A[(size_t)(i0 + row) * K + (t) * 64 + kk * 32 + (cb >> 1)],           \
                &As[sl][kk][s * 512]);                                                 \
        gload16(&Bt[(size_t)(n0 + row) * K + (t) * 64 + kk * 32 + (cb >> 1)],          \
                &Bs[sl][kk][s * 512]);                                                 \
      }                                                                                \
    }                                                                                  \
  }

// ---------- merged projection GEMM (round-17 proven): 256x128 tile, wave 128x64 ----------
__global__ __launch_bounds__(256, 2) void k_gemm_qkvg(const u16* __restrict__ A, const u16* __restrict__ Bt,
                                                      float* __restrict__ qk, u16* __restrict__ vg,
                                                      const float2* __restrict__ tab, int K) {
  __shared__ __attribute__((aligned(16))) u16 As[2][256 * 32];
  __shared__ __attribute__((aligned(16))) u16 Bs[2][128 * 32];
  int nbx = gridDim.x;
  int id = blockIdx.y * nbx + blockIdx.x;
  int cpx = (nbx * gridDim.y) >> 3;
  int sw = (id & 7) * cpx + (id >> 3);
  int bx = sw % nbx, by = sw / nbx;
  int i0 = by * 256, n0 = bx * 128;
  int tid = threadIdx.x;
  int lane = tid & 63, w = tid >> 6;
  int wr = (w >> 1) * 128, wc = (w & 1) * 64;
  f32x4 acc[8][4];
#pragma unroll
  for (int m = 0; m < 8; ++m)
#pragma unroll
    for (int n = 0; n < 4; ++n) acc[m][n] = (f32x4){0.f, 0.f, 0.f, 0.f};
  int fr = lane & 15, kq = lane >> 4;
  int nkt = K >> 5;

  STG_P(0, 0);
  bar_vm();
  for (int t = 0; t < nkt; ++t) {
    int sl = t & 1;
    if (t + 1 < nkt) STG_P(t + 1, sl ^ 1);
    bf16x8 af[8], bfr[4];
#pragma unroll
    for (int m = 0; m < 8; ++m) {
      int rr = wr + m * 16 + fr;
      int idx = (rr * 32 + kq * 8) ^ (((rr >> 3) & 1) << 4);
      af[m] = *(const bf16x8*)&As[sl][idx];
    }
#pragma unroll
    for (int n = 0; n < 4; ++n) {
      int rr = wc + n * 16 + fr;
      int idx = (rr * 32 + kq * 8) ^ (((rr >> 3) & 1) << 4);
      bfr[n] = *(const bf16x8*)&Bs[sl][idx];
    }
    __builtin_amdgcn_s_setprio(1);
#pragma unroll
    for (int m = 0; m < 8; ++m)
#pragma unroll
      for (int n = 0; n < 4; ++n)
        acc[m][n] = __builtin_amdgcn_mfma_f32_16x16x32_bf16(af[m], bfr[n], acc[m][n], 0, 0, 0);
    __builtin_amdgcn_s_setprio(0);
    bar_vm();
  }

  int rb = (lane >> 4) * 4, cb2 = lane & 15;
  if (n0 < 2048) {
    float scale = (n0 < 1024) ? 0.125f : 1.0f;
#pragma unroll
    for (int m = 0; m < 8; ++m)
#pragma unroll
      for (int n = 0; n < 2; ++n) {
        int gc = n0 + wc + n * 16 + cb2;
        int ii = n * 16 + cb2;
#pragma unroll
        for (int r = 0; r < 4; ++r) {
          int gr = i0 + wr + m * 16 + rb + r;
          int t = gr & 2047;
          float2 cs = tab[t * 32 + ii];
          float q1 = acc[m][n][r], q2 = acc[m][n + 2][r];
          qk[(size_t)gr * 2048 + gc]      = (q1 * cs.x - q2 * cs.y) * scale;
          qk[(size_t)gr * 2048 + gc + 32] = (q2 * cs.x + q1 * cs.y) * scale;
        }
      }
  } else {
#pragma unroll
    for (int m = 0; m < 8; ++m)
#pragma unroll
      for (int n = 0; n < 4; ++n) {
        int gr = i0 + wr + m * 16 + rb;
        int gc = n0 - 2048 + wc + n * 16 + cb2;
#pragma unroll
        for (int r = 0; r < 4; ++r)
          vg[(size_t)(gr + r) * 4096 + gc] = f2bf(acc[m][n][r]);
      }
  }
}

// ---------- output GEMM (round-16 proven): 128x128 tile, BK=64 dbuf ----------
__global__ __launch_bounds__(256, 2) void k_gemm_out(const u16* __restrict__ A, const u16* __restrict__ Bt,
                                                     float* __restrict__ Cv, int N, int K) {
  __shared__ __attribute__((aligned(16))) u16 As[2][2][128 * 32];
  __shared__ __attribute__((aligned(16))) u16 Bs[2][2][128 * 32];
  int nbx = gridDim.x;
  int id = blockIdx.y * nbx + blockIdx.x;
  int cpx = (nbx * gridDim.y) >> 3;
  int sw = (id & 7) * cpx + (id >> 3);
  int bx = sw % nbx, by = sw / nbx;
  int i0 = by * 128, n0 = bx * 128;
  int tid = threadIdx.x;
  int lane = tid & 63, w = tid >> 6;
  int wr = (w >> 1) * 64, wc = (w & 1) * 64;
  f32x4 acc[4][4];
#pragma unroll
  for (int m = 0; m < 4; ++m)
#pragma unroll
    for (int n = 0; n < 4; ++n) acc[m][n] = (f32x4){0.f, 0.f, 0.f, 0.f};
  int fr = lane & 15, kq = lane >> 4;
  int nkt = K >> 6;

  STG64_O(0, 0);
  bar_vm();
  for (int t = 0; t < nkt; ++t) {
    int sl = t & 1;
    if (t + 1 < nkt) STG64_O(t + 1, sl ^ 1);
#pragma unroll
    for (int kk = 0; kk < 2; ++kk) {
      bf16x8 af[4], bfr[4];
#pragma unroll
      for (int m = 0; m < 4; ++m) {
        int rr = wr + m * 16 + fr;
        int idx = (rr * 32 + kq * 8) ^ (((rr >> 3) & 1) << 4);
        af[m] = *(const bf16x8*)&As[sl][kk][idx];
      }
#pragma unroll
      for (int n = 0; n < 4; ++n) {
        int rr = wc + n * 16 + fr;
        int idx = (rr * 32 + kq * 8) ^ (((rr >> 3) & 1) << 4);
        bfr[n] = *(const bf16x8*)&Bs[sl][kk][idx];
      }
      __builtin_amdgcn_s_setprio(1);
#pragma unroll
      for (int m = 0; m < 4; ++m)
#pragma unroll
        for (int n = 0; n < 4; ++n)
          acc[m][n] = __builtin_amdgcn_mfma_f32_16x16x32_bf16(af[m], bfr[n], acc[m][n], 0, 0, 0);
      __builtin_amdgcn_s_setprio(0);
    }
    bar_vm();
  }

  int rb = (lane >> 4) * 4, cb2 = lane & 15;
#pragma unroll
  for (int m = 0; m < 4; ++m)
#pragma unroll
    for (int n = 0; n < 4; ++n) {
      int gr = i0 + wr + m * 16 + rb;
      int gc = n0 + wc + n * 16 + cb2;
#pragma unroll
      for (int r = 0; r < 4; ++r)
        Cv[(size_t)(gr + r) * N + gc] = acc[m][n][r];
    }
}

// ---------- Fused retention v7 (proven, frozen) ----------
__global__ __launch_bounds__(512) void k_retention(const float* __restrict__ qk, const u16* __restrict__ vg,
                                                   const float* __restrict__ gnw, u16* __restrict__ og) {
  int bh = blockIdx.x & 63, rq = blockIdx.x >> 6;
  int h = bh & 15, b = bh >> 4;
  int gi0 = rq * 16;

  __shared__ __attribute__((aligned(16))) float qs[16][68];
  __shared__ __attribute__((aligned(16))) float ks[64][68];
  __shared__ __attribute__((aligned(16))) u16 vst[128][88];
  __shared__ __attribute__((aligned(16))) u16 kta_h[8][520];
  __shared__ __attribute__((aligned(16))) u16 kta_l[8][520];
  __shared__ __attribute__((aligned(16))) u16 pa_h[16][68];
  __shared__ __attribute__((aligned(16))) u16 pa_l[16][68];
  __shared__ __attribute__((aligned(16))) u16 sst_h[8][1040];
  __shared__ __attribute__((aligned(16))) u16 sst_l[8][1040];
  __shared__ float dpow[72];
  __shared__ float ssred[8][16];

  int tid = threadIdx.x;
  int w = tid >> 6, l = tid & 63;
  int fr = l & 15, fq = l >> 4;
  float gamma = 1.f - exp2f(-5.f - (float)h);
  if (tid <= 64) dpow[tid] = powf(gamma, (float)tid);
  for (int c = tid; c < 4160; c += 512) { ((u32*)sst_h)[c] = 0; ((u32*)sst_l)[c] = 0; }
  __syncthreads();
  float cdec = dpow[64];

  int e0 = w * 16;
  float gww = gnw[e0 + fr];
  int khmax = (rq < 2) ? 1 : 2;

  int qi = tid >> 4, qd4 = (tid & 15) * 4;
  int sj = tid >> 3, sdg = (tid & 7) * 8;
  int vjp = tid & 31, ve8 = (tid >> 5) * 8;

  f32x4 Sacc[4][2];
#pragma unroll
  for (int dt = 0; dt < 4; ++dt)
#pragma unroll
    for (int nt = 0; nt < 2; ++nt) Sacc[dt][nt] = (f32x4){0.f, 0.f, 0.f, 0.f};

  f32x4 pq = (f32x4){0.f, 0.f, 0.f, 0.f};
  f32x4 pk0, pk1;
  bf16x8 pva, pvb;
  {
    int rowbase = b * 2048;
    if (tid < 256) pq = *(const f32x4*)&qk[(size_t)(rowbase + gi0 + qi) * 2048 + h * 64 + qd4];
    const float* kr = &qk[(size_t)(rowbase + sj) * 2048 + 1024 + h * 64 + sdg];
    pk0 = *(const f32x4*)kr;
    pk1 = *(const f32x4*)(kr + 4);
    const u16* vr = &vg[(size_t)(rowbase + 2 * vjp) * 4096 + h * 128 + ve8];
    pva = *(const bf16x8*)vr;
    pvb = *(const bf16x8*)(vr + 4096);
  }

  for (int n = 0; n < 32; ++n) {
    int rowbase = b * 2048 + n * 64;
    if (tid < 256) *(f32x4*)&qs[qi][qd4] = pq;
    {
      *(f32x4*)&ks[sj][sdg] = pk0;
      *(f32x4*)&ks[sj][sdg + 4] = pk1;
      float kdv = dpow[63 - sj];
      float kd[8];
#pragma unroll
      for (int m = 0; m < 4; ++m) { kd[m] = pk0[m] * kdv; kd[m + 4] = pk1[m] * kdv; }
      bf16x8 kh8, kl8;
      split8r(kd, kh8, kl8);
      int J = sj >> 3, s = sj & 7, dh = tid & 7;
#pragma unroll
      for (int m = 0; m < 8; ++m) {
        int blk = (dh * 8) | (m ^ dh);
        kta_h[J][blk * 8 + s] = (u16)kh8[m];
        kta_l[J][blk * 8 + s] = (u16)kl8[m];
      }
#pragma unroll
      for (int m = 0; m < 8; ++m)
        *(u32*)&vst[ve8 + m][2 * vjp] = (u32)(u16)pva[m] | ((u32)(u16)pvb[m] << 16);
    }
    __syncthreads();
    if (n < 31) {
      int rb2 = rowbase + 64;
      if (tid < 256) pq = *(const f32x4*)&qk[(size_t)(rb2 + gi0 + qi) * 2048 + h * 64 + qd4];
      const float* kr = &qk[(size_t)(rb2 + sj) * 2048 + 1024 + h * 64 + sdg];
      pk0 = *(const f32x4*)kr;
      pk1 = *(const f32x4*)(kr + 4);
      const u16* vr = &vg[(size_t)(rb2 + 2 * vjp) * 4096 + h * 128 + ve8];
      pva = *(const bf16x8*)vr;
      pvb = *(const bf16x8*)(vr + 4096);
    }
    bf16x8 qhc[2], qlc[2];
    split8p(&qs[fr][fq * 8], qhc[0], qlc[0]);
    split8p(&qs[fr][32 + fq * 8], qhc[1], qlc[1]);
    if (w < 4) {
      int ct = w;
      f32x4 at = (f32x4){0.f, 0.f, 0.f, 0.f};
      if (16 * ct <= gi0 + 15) {
#pragma unroll
        for (int kh = 0; kh < 2; ++kh) {
          bf16x8 kbh, kbl;
          split8p(&ks[16 * ct + fr][kh * 32 + fq * 8], kbh, kbl);
          at = __builtin_amdgcn_mfma_f32_16x16x32_bf16(kbh, qhc[kh], at, 0, 0, 0);
          at = __builtin_amdgcn_mfma_f32_16x16x32_bf16(kbl, qhc[kh], at, 0, 0, 0);
          at = __builtin_amdgcn_mfma_f32_16x16x32_bf16(kbh, qlc[kh], at, 0, 0, 0);
        }
      }
      int jb = 16 * ct + fq * 4;
      ushort4 wh, wl;
#pragma unroll
      for (int r = 0; r < 4; ++r) {
        int s = gi0 + fr - (jb + r);
        float val = (s >= 0) ? at[r] * dpow[s] : 0.f;
        union { float f; u32 u; } c; c.f = val;
        union { u32 u; float f; } hf; hf.u = c.u & 0xffff0000u;
        union { float f; u32 u; } lw; lw.f = val - hf.f;
        ((u16*)&wh)[r] = (u16)(c.u >> 16);
        ((u16*)&wl)[r] = (u16)(lw.u >> 16);
      }
      *(ushort4*)&pa_h[fr][jb] = wh;
      *(ushort4*)&pa_l[fr][jb] = wl;
    } else if (n < 31) {
      int eb = (w - 4) * 32;
#pragma unroll
      for (int dt = 0; dt < 4; ++dt)
#pragma unroll
        for (int nt = 0; nt < 2; ++nt)
#pragma unroll
          for (int r = 0; r < 4; ++r) Sacc[dt][nt][r] *= cdec;
      bf16x8 bv[2][2];
#pragma unroll
      for (int kh2 = 0; kh2 < 2; ++kh2)
#pragma unroll
        for (int nt = 0; nt < 2; ++nt)
          bv[kh2][nt] = *(const bf16x8*)&vst[eb + nt * 16 + fr][kh2 * 32 + fq * 8];
#pragma unroll
      for (int kh2 = 0; kh2 < 2; ++kh2) {
#pragma unroll
        for (int dt = 0; dt < 4; ++dt) {
          int d = dt * 16 + fr;
          int blk = d ^ ((dt * 2 + (fr >> 3)) & 7);
          bf16x8 ah = *(const bf16x8*)&kta_h[kh2 * 4 + fq][blk * 8];
          bf16x8 al = *(const bf16x8*)&kta_l[kh2 * 4 + fq][blk * 8];
#pragma unroll
          for (int nt = 0; nt < 2; ++nt) {
            Sacc[dt][nt] = __builtin_amdgcn_mfma_f32_16x16x32_bf16(ah, bv[kh2][nt], Sacc[dt][nt], 0, 0, 0);
            Sacc[dt][nt] = __builtin_amdgcn_mfma_f32_16x16x32_bf16(al, bv[kh2][nt], Sacc[dt][nt], 0, 0, 0);
          }
        }
      }
    }
    bar_lds();
    f32x4 o1 = (f32x4){0.f, 0.f, 0.f, 0.f};
    f32x4 o2 = (f32x4){0.f, 0.f, 0.f, 0.f};
#pragma unroll
    for (int kh2 = 0; kh2 < 2; ++kh2) {
      bf16x8 sh = *(const bf16x8*)&sst_h[kh2 * 4 + fq][(e0 + fr) * 8];
      bf16x8 sl = *(const bf16x8*)&sst_l[kh2 * 4 + fq][(e0 + fr) * 8];
      o2 = __builtin_amdgcn_mfma_f32_16x16x32_bf16(qhc[kh2], sh, o2, 0, 0, 0);
      o2 = __builtin_amdgcn_mfma_f32_16x16x32_bf16(qhc[kh2], sl, o2, 0, 0, 0);
      o2 = __builtin_amdgcn_mfma_f32_16x16x32_bf16(qlc[kh2], sh, o2, 0, 0, 0);
      if (kh2 < khmax) {
        bf16x8 ph = *(const bf16x8*)&pa_h[fr][kh2 * 32 + fq * 8];
        bf16x8 pl = *(const bf16x8*)&pa_l[fr][kh2 * 32 + fq * 8];
        bf16x8 bvv = *(const bf16x8*)&vst[e0 + fr][kh2 * 32 + fq * 8];
        o1 = __builtin_amdgcn_mfma_f32_16x16x32_bf16(ph, bvv, o1, 0, 0, 0);
        o1 = __builtin_amdgcn_mfma_f32_16x16x32_bf16(pl, bvv, o1, 0, 0, 0);
      }
    }
    float ofin[4], ssp[4];
#pragma unroll
    for (int r = 0; r < 4; ++r) {
      int gi = gi0 + fq * 4 + r;
      ofin[r] = o1[r] + dpow[gi + 1] * o2[r];
      ssp[r] = ofin[r] * ofin[r];
    }
#pragma unroll
    for (int r = 0; r < 4; ++r) {
      ssp[r] += __shfl_xor(ssp[r], 1, 64);
      ssp[r] += __shfl_xor(ssp[r], 2, 64);
      ssp[r] += __shfl_xor(ssp[r], 4, 64);
      ssp[r] += __shfl_xor(ssp[r], 8, 64);
    }
    if (fr == 0) {
#pragma unroll
      for (int r = 0; r < 4; ++r) ssred[w][fq * 4 + r] = ssp[r];
    }
    bar_lds();
#pragma unroll
    for (int r = 0; r < 4; ++r) {
      int i16 = fq * 4 + r;
      float tot = 0.f;
#pragma unroll
      for (int w2 = 0; w2 < 8; ++w2) tot += ssred[w2][i16];
      float rms = rsqrtf(tot * (1.f / 128.f) + 1e-5f);
      int grow = rowbase + gi0 + i16;
      float g = bf2f(vg[(size_t)grow * 4096 + 2048 + h * 128 + e0 + fr]);
      float y = ofin[r] * rms * gww * (g / (1.f + expf(-g)));
      og[(size_t)grow * 2048 + h * 128 + e0 + fr] = f2bf(y);
    }
    if (w >= 4 && n < 31) {
      int eb = (w - 4) * 32;
#pragma unroll
      for (int dt = 0; dt < 4; ++dt) {
        int g = dt * 2 + (fq >> 1);
#pragma unroll
        for (int nt = 0; nt < 2; ++nt) {
          int e = eb + nt * 16 + fr;
          ushort4 wh, wl;
#pragma unroll
          for (int r = 0; r < 4; ++r) {
            union { float f; u32 u; } c; c.f = Sacc[dt][nt][r];
            union { u32 u; float f; } hf; hf.u = c.u & 0xffff0000u;
            union { float f; u32 u; } lw; lw.f = Sacc[dt][nt][r] - hf.f;
            ((u16*)&wh)[r] = (u16)(c.u >> 16);
            ((u16*)&wl)[r] = (u16)(lw.u >> 16);
          }
          int idx = e * 8 + (fq & 1) * 4;
          *(ushort4*)&sst_h[g][idx] = wh;
          *(ushort4*)&sst_l[g][idx] = wl;
        }
      }
    }
  }
}

extern "C" void kernel_launch(void* const* d_in, const int* in_sizes, int n_in,
                              void* d_out, int out_size, void* d_ws, size_t ws_size,
                              hipStream_t stream) {
  const float* x   = (const float*)d_in[0];
  const float* Wq  = (const float*)d_in[1];
  const float* Wk  = (const float*)d_in[2];
  const float* Wv  = (const float*)d_in[3];
  const float* Wg  = (const float*)d_in[4];
  const float* Wo  = (const float*)d_in[5];
  const float* gnw = (const float*)d_in[6];
  float* out = (float*)d_out;

  const size_t MB = 1024 * 1024;
  char* ws = (char*)d_ws;
  u16*   xb   = (u16*)(ws + 0 * MB);
  u16*   Wqkb = (u16*)(ws + 16 * MB);     // [2048][1024]
  u16*   Wvgb = (u16*)(ws + 20 * MB);     // [4096][1024]
  float2* tab = (float2*)(ws + 28 * MB);  // 512 KB rope table
  float* qk   = (float*)(ws + 32 * MB);
  u16*   vg   = (u16*)(ws + 96 * MB);
  u16*   Wob  = (u16*)(ws + 160 * MB);
  u16*   og   = (u16*)(ws + 0 * MB);      // overlay (xb/W dead by then)
  const size_t NEED = 164 * MB;
  if (ws_size < NEED) {
    k_sentinel<<<1, 64, 0, stream>>>(out);
    return;
  }

  k_cvt_x<<<8192, 256, 0, stream>>>(x, xb);
  k_ropetab<<<256, 256, 0, stream>>>(tab);
  k_transpose_all<<<8192, 256, 0, stream>>>(Wq, Wk, Wv, Wg, Wo, Wqkb, Wvgb, Wob);

  k_gemm_qkvg<<<dim3(48, 32), 256, 0, stream>>>(xb, Wqkb, qk, vg, tab, 1024);
  k_retention<<<256, 512, 0, stream>>>(qk, vg, gnw, og);
  k_gemm_out<<<dim3(8, 64), 256, 0, stream>>>(og, Wob, out, 1024, 2048);
}